// Round 4
// baseline (565.145 us; speedup 1.0000x reference)
//
#include <hip/hip_runtime.h>
#include <stdint.h>

// ---------------------------------------------------------------------------
// QuantizedLinear via int8 MFMA: y[m,n] = s_x*s_w * (xq @ wq^T)[m,n] + bias[n]
// W int8 exact; x quantized at 6/127 (clamp +-6). int32 accum exact.
//
// R6 (3rd submit; rounds 2-3 died at container acquisition — same infra
// error hit the known-good R4 kernel in round 0; audit found no fault/hang
// path in this source):
//   single-barrier read-ahead phases (overlap ds_read with MFMA).
//   Phase p body: barrier; lgkmcnt(0) [frags read-issued at p-1 are done];
//   issue ds_reads for p+1; issue this phase's stage gloads; MFMA x16
//   (k-step0 cluster then k-step1, dep distance 8); counted VMCNT; loop.
//   LDS reads complete under the ~650-cyc MFMA shadow -> next lgkm(0) free.
//
//   Per iteration (T0=2i in buf0, T1=2i+1 in buf1), QA-major Gray order:
//   P1(0,0) P2(0,1) P3(1,1) P4(1,0) | P5-P8 same on T1.
//   Frag regs ping-pong (disjoint from each phase's MFMA operands):
//     reads@P8': A0(T0)->aP, B0(T0)->bX   | P1: B1(T0)->bY
//     P2: A1(T0)->aQ, B0(T0)re->bX        | P4: A0(T1)->aP, B0(T1)->bY
//     P5: B1(T1)->bX                      | P6: A1(T1)->aQ, B0(T1)re->bY
//     P8: A0(T0+2)->aP, B0(T0+2)->bX
//   56 ds_read_b128 / wave / 2-K-tiles (was 64).
//
//   Stages (one half per phase; half staged >= 2 phases after the region's
//   last read-issue => all WAR safe via [reader lgkm drain at q+1] < barrier):
//     P2:A0(T0+2) P3:B1(T0+2) P4:A1(T0+2) P5:B0(T0+2)
//     P6:A0(T1+2) P7:B1(T1+2) P8:A1(T1+2)+B0(T1+2)
//   vmcnt guards (pre-next-barrier, wave-outstanding counted, derived):
//     end-P1: VMCNT(8)  forces P4',P5'  (A1,B0re read @P2)
//     end-P3: VMCNT(4)  forces P6',P7',P8' (A0/B0 of T1 read @P4)
//     end-P7: VMCNT(4)  forces P5 (B0(T0+2) read @P8)
//     end-P8: VMCNT(12) forces P3 (B1(T0+2) read @next-P1)
//   All guards target loads >=2 phases (~1500 cyc) old -> no stall.
//   Last iteration peeled: no stages, end-P3 VMCNT(0), no P8 reads.
//
//   Chunk-XOR swizzle kept (R4/R5, bank-conflict counter measured 0):
//   LDS(r,p) holds global chunk p^(r&7); conflict-free at quarter-wave
//   granularity for ds_read_b128.
// ---------------------------------------------------------------------------

#define M_TOT 8192
#define N_TOT 4096
#define K_TOT 4096
#define BM 256
#define BN 256
#define BK 128              // i8 elements = 128 B per tile row = 8 x 16B chunks
#define NT (K_TOT / BK)     // 32 k-tiles

#define XCLAMP 6.0f

typedef int i32x4 __attribute__((ext_vector_type(4)));

__device__ __forceinline__ int q8(float v, float r) {
    float c = fminf(fmaxf(v * r, -127.0f), 127.0f);
    return (int)rintf(c);
}

__global__ __launch_bounds__(256) void cvt_fused(
    const float4* __restrict__ x, const int4* __restrict__ w,
    unsigned* __restrict__ xq, unsigned* __restrict__ wq, int nx4, int nw4) {
    int i = blockIdx.x * blockDim.x + threadIdx.x;
    if (i < nx4) {
        const float r = 127.0f / XCLAMP;
        float4 v = x[i];
        xq[i] = (unsigned)(q8(v.x, r) & 0xff)
              | ((unsigned)(q8(v.y, r) & 0xff) << 8)
              | ((unsigned)(q8(v.z, r) & 0xff) << 16)
              | ((unsigned)(q8(v.w, r) & 0xff) << 24);
    } else {
        int j = i - nx4;
        if (j >= nw4) return;
        int4 a = w[j];
        wq[j] = (unsigned)(a.x & 0xff)
              | ((unsigned)(a.y & 0xff) << 8)
              | ((unsigned)(a.z & 0xff) << 16)
              | ((unsigned)(a.w & 0xff) << 24);
    }
}

#define GLOAD_LDS16(gptr, lptr)                                                  \
    __builtin_amdgcn_global_load_lds(                                            \
        (const __attribute__((address_space(1))) void*)(gptr),                   \
        (__attribute__((address_space(3))) void*)(lptr), 16, 0, 0)

#define VMCNT(n) asm volatile("s_waitcnt vmcnt(" #n ")" ::: "memory")
#define NOSTG ((void)0)
#define NOCKPT ((void)0)

// Stage one A half-tile (q = 0/1): 8 waves x 2 wave-loads of 8 rows each.
// A half q = rows {seg*128 + q*64 .. +64) for seg=0,1.
#define STAGE_A(GP, LB, q)                                                       \
    { _Pragma("unroll")                                                          \
      for (int l = 0; l < 2; ++l) {                                              \
          const int s_  = (wave << 1) | l;                                       \
          const int r0_ = ((s_ >> 3) << 7) | ((q) << 6) | ((s_ & 7) << 3);       \
          GLOAD_LDS16((GP) + (size_t)(r0_ + srow) * K_TOT + scol,                \
                      (LB) + r0_ * BK);                                          \
      } }

// B half q = rows {seg*64 + q*32 .. +32) for seg=0..3.
#define STAGE_B(GP, LB, q)                                                       \
    { _Pragma("unroll")                                                          \
      for (int l = 0; l < 2; ++l) {                                              \
          const int s_  = (wave << 1) | l;                                       \
          const int r0_ = ((s_ >> 2) << 6) | ((q) << 5) | ((s_ & 3) << 3);       \
          GLOAD_LDS16((GP) + (size_t)(r0_ + srow) * K_TOT + scol,                \
                      (LB) + r0_ * BK);                                          \
      } }

// Fragment reads: 8 (A) / 4 (B) ds_read_b128 into named ping-pong regs.
#define READ_A(D0, D1, BUF, QA)                                                  \
    { _Pragma("unroll")                                                          \
      for (int i = 0; i < 4; ++i) {                                              \
          const int rb = (wm + (QA) * 64 + i * 16 + frow) * BK;                  \
          D0[i] = *(const i32x4*)((BUF) + rb + pos0);                            \
          D1[i] = *(const i32x4*)((BUF) + rb + pos1);                            \
      } }

#define READ_B(D0, D1, BUF, QB)                                                  \
    { _Pragma("unroll")                                                          \
      for (int j = 0; j < 2; ++j) {                                              \
          const int rb = (wn + (QB) * 32 + j * 16 + frow) * BK;                  \
          D0[j] = *(const i32x4*)((BUF) + rb + pos0);                            \
          D1[j] = *(const i32x4*)((BUF) + rb + pos1);                            \
      } }

// One phase: barrier; drain my frag reads (issued last phase, completed
// under last phase's MFMA); issue next phase's reads + this phase's stages;
// 16 MFMA (k-step0 cluster then k-step1: same-acc dep distance 8); ckpt.
#define PHASE(READS, STAGES, QA, QB, A0, A1, B0, B1, CKPT)                       \
    {                                                                            \
        __builtin_amdgcn_s_barrier();                                            \
        asm volatile("s_waitcnt lgkmcnt(0)" ::: "memory");                       \
        __builtin_amdgcn_sched_barrier(0);                                       \
        READS;                                                                   \
        STAGES;                                                                  \
        __builtin_amdgcn_sched_barrier(0);                                       \
        __builtin_amdgcn_s_setprio(1);                                           \
        _Pragma("unroll")                                                        \
        for (int i = 0; i < 4; ++i)                                              \
            _Pragma("unroll")                                                    \
            for (int j = 0; j < 2; ++j)                                          \
                acc[(QA) * 4 + i][(QB) * 2 + j] =                                \
                    __builtin_amdgcn_mfma_i32_16x16x64_i8(                       \
                        A0[i], B0[j], acc[(QA) * 4 + i][(QB) * 2 + j], 0, 0, 0); \
        _Pragma("unroll")                                                        \
        for (int i = 0; i < 4; ++i)                                              \
            _Pragma("unroll")                                                    \
            for (int j = 0; j < 2; ++j)                                          \
                acc[(QA) * 4 + i][(QB) * 2 + j] =                                \
                    __builtin_amdgcn_mfma_i32_16x16x64_i8(                       \
                        A1[i], B1[j], acc[(QA) * 4 + i][(QB) * 2 + j], 0, 0, 0); \
        __builtin_amdgcn_s_setprio(0);                                           \
        CKPT;                                                                    \
    }

// C = A(MxK,i8) * B(NxK,i8)^T, epilogue: out = (s_x*s_w)*acc_i32 + bias[n]
__global__ __launch_bounds__(512, 2) void gemm_i8(
    const signed char* __restrict__ A, const signed char* __restrict__ B,
    const float* __restrict__ scale, const float* __restrict__ bias,
    float* __restrict__ out) {
    __shared__ alignas(16) signed char As0[BM * BK];  // 32 KB  (tile even)
    __shared__ alignas(16) signed char Bs0[BN * BK];  // 32 KB
    __shared__ alignas(16) signed char As1[BM * BK];  // 32 KB  (tile odd)
    __shared__ alignas(16) signed char Bs1[BN * BK];  // 32 KB

    const int tid  = threadIdx.x;
    const int wave = tid >> 6;
    const int lane = tid & 63;
    const int bm = blockIdx.x;            // 0..31
    const int bn = blockIdx.y;            // 0..15
    const int wm = (wave >> 2) * 128;     // 2 wave-rows
    const int wn = (wave & 3) * 64;       // 4 wave-cols

    // fragment read coords: row R, k-chunk g = lane>>4 (+4 for k-step 1);
    // chunk g sits at LDS pos g ^ (R&7), R&7 == lane&7 for all frag rows.
    const int frow = lane & 15;
    const int pos0 = (((lane >> 4) + 0) ^ (lane & 7)) << 4;
    const int pos1 = (((lane >> 4) + 4) ^ (lane & 7)) << 4;
    // staging source coords (pre-swizzled global chunk)
    const int srow = lane >> 3;
    const int scol = ((lane & 7) ^ (lane >> 3)) << 4;

    const signed char* Ag = A + (size_t)bm * BM * K_TOT;
    const signed char* Bg = B + (size_t)bn * BN * K_TOT;

    i32x4 acc[8][4] = {};
    i32x4 aP0[4], aP1[4], aQ0[4], aQ1[4];   // A halves, ping-pong
    i32x4 bX0[2], bX1[2], bY0[2], bY1[2];   // B halves, ping-pong

    // ---- prologue: stage T0->buf0, T1->buf1 in steady-state slot order ----
    STAGE_A(Ag, As0, 0);        // A0(T0)   (P2 slot)
    STAGE_B(Bg, Bs0, 1);        // B1(T0)   (P3 slot)
    STAGE_A(Ag, As0, 1);        // A1(T0)   (P4 slot)
    STAGE_B(Bg, Bs0, 0);        // B0(T0)   (P5 slot)
    STAGE_A(Ag + BK, As1, 0);   // A0(T1)   (P6 slot)
    STAGE_B(Bg + BK, Bs1, 1);   // B1(T1)   (P7 slot)
    STAGE_A(Ag + BK, As1, 1);   // A1(T1)   (P8 slot)
    STAGE_B(Bg + BK, Bs1, 0);   // B0(T1)   (P8 slot)
    VMCNT(8);                   // all of buf0 (oldest 8 loads) landed
    __builtin_amdgcn_s_barrier();
    // "P8 of iter -1": issue reads for P1
    READ_A(aP0, aP1, As0, 0);   // A0(T0) -> aP
    READ_B(bX0, bX1, Bs0, 0);   // B0(T0) -> bX

    // ---- main loop: 15 full iterations, 2 K-tiles each, 8 phases ----
#pragma unroll 1
    for (int t0 = 0; t0 < NT - 2; t0 += 2) {
        const signed char* An  = Ag + (size_t)(t0 + 2) * BK;
        const signed char* Bn  = Bg + (size_t)(t0 + 2) * BK;
        const signed char* An1 = Ag + (size_t)(t0 + 3) * BK;
        const signed char* Bn1 = Bg + (size_t)(t0 + 3) * BK;

        // P1 (0,0)T0: aP,bX | read B1(T0)->bY
        PHASE(READ_B(bY0, bY1, Bs0, 1), NOSTG,
              0, 0, aP0, aP1, bX0, bX1, VMCNT(8))
        // P2 (0,1)T0: aP,bY | read A1(T0)->aQ, B0(T0)re->bX | stage A0(T0+2)
        PHASE(READ_A(aQ0, aQ1, As0, 1); READ_B(bX0, bX1, Bs0, 0),
              STAGE_A(An, As0, 0),
              0, 1, aP0, aP1, bY0, bY1, NOCKPT)
        // P3 (1,1)T0: aQ,bY | stage B1(T0+2)
        PHASE(NOSTG, STAGE_B(Bn, Bs0, 1),
              1, 1, aQ0, aQ1, bY0, bY1, VMCNT(4))
        // P4 (1,0)T0: aQ,bX | read A0(T1)->aP, B0(T1)->bY | stage A1(T0+2)
        PHASE(READ_A(aP0, aP1, As1, 0); READ_B(bY0, bY1, Bs1, 0),
              STAGE_A(An, As0, 1),
              1, 0, aQ0, aQ1, bX0, bX1, NOCKPT)
        // P5 (0,0)T1: aP,bY | read B1(T1)->bX | stage B0(T0+2)
        PHASE(READ_B(bX0, bX1, Bs1, 1), STAGE_B(Bn, Bs0, 0),
              0, 0, aP0, aP1, bY0, bY1, NOCKPT)
        // P6 (0,1)T1: aP,bX | read A1(T1)->aQ, B0(T1)re->bY | stage A0(T1+2)
        PHASE(READ_A(aQ0, aQ1, As1, 1); READ_B(bY0, bY1, Bs1, 0),
              STAGE_A(An1, As1, 0),
              0, 1, aP0, aP1, bX0, bX1, NOCKPT)
        // P7 (1,1)T1: aQ,bX | stage B1(T1+2)
        PHASE(NOSTG, STAGE_B(Bn1, Bs1, 1),
              1, 1, aQ0, aQ1, bX0, bX1, VMCNT(4))
        // P8 (1,0)T1: aQ,bY | read A0(T0+2)->aP, B0(T0+2)->bX
        //            | stage A1(T1+2), B0(T1+2)
        PHASE(READ_A(aP0, aP1, As0, 0); READ_B(bX0, bX1, Bs0, 0),
              STAGE_A(An1, As1, 1); STAGE_B(Bn1, Bs1, 0),
              1, 0, aQ0, aQ1, bY0, bY1, VMCNT(12))
    }

    // ---- peeled last iteration (tiles NT-2, NT-1): no stages, drain ----
    PHASE(READ_B(bY0, bY1, Bs0, 1), NOSTG, 0, 0, aP0, aP1, bX0, bX1, VMCNT(8))
    PHASE(READ_A(aQ0, aQ1, As0, 1); READ_B(bX0, bX1, Bs0, 0), NOSTG,
          0, 1, aP0, aP1, bY0, bY1, NOCKPT)
    PHASE(NOSTG, NOSTG, 1, 1, aQ0, aQ1, bY0, bY1, VMCNT(0))
    PHASE(READ_A(aP0, aP1, As1, 0); READ_B(bY0, bY1, Bs1, 0), NOSTG,
          1, 0, aQ0, aQ1, bX0, bX1, NOCKPT)
    PHASE(READ_B(bX0, bX1, Bs1, 1), NOSTG, 0, 0, aP0, aP1, bY0, bY1, NOCKPT)
    PHASE(READ_A(aQ0, aQ1, As1, 1); READ_B(bY0, bY1, Bs1, 0), NOSTG,
          0, 1, aP0, aP1, bX0, bX1, NOCKPT)
    PHASE(NOSTG, NOSTG, 1, 1, aQ0, aQ1, bX0, bX1, NOCKPT)
    PHASE(NOSTG, NOSTG, 1, 0, aQ0, aQ1, bY0, bY1, NOCKPT)

    // epilogue: C/D layout col=lane&15, row=(lane>>4)*4+reg (dtype-independent)
    const float s = scale[0] * (XCLAMP / 127.0f);
    const int colq = lane & 15;
    const int rowq = (lane >> 4) * 4;
#pragma unroll
    for (int ii = 0; ii < 8; ++ii) {
        const int rbase = bm * BM + wm + (ii >> 2) * 64 + (ii & 3) * 16 + rowq;
#pragma unroll
        for (int jj = 0; jj < 4; ++jj) {
            const int c = bn * BN + wn + (jj >> 1) * 32 + (jj & 1) * 16 + colq;
            const float bv = bias[c];
#pragma unroll
            for (int r = 0; r < 4; ++r)
                out[(size_t)(rbase + r) * N_TOT + c] = s * (float)acc[ii][jj][r] + bv;
        }
    }
}

extern "C" void kernel_launch(void* const* d_in, const int* in_sizes, int n_in,
                              void* d_out, int out_size, void* d_ws, size_t ws_size,
                              hipStream_t stream) {
    const float* x     = (const float*)d_in[0];   // [8192, 4096] fp32
    const int*   w     = (const int*)d_in[1];     // [4096, 4096] int32
    const float* scale = (const float*)d_in[2];   // [1]
    const float* bias  = (const float*)d_in[3];   // [4096]
    float* out = (float*)d_out;

    signed char* Xq = (signed char*)d_ws;                           // 32 MiB
    signed char* Wq = (signed char*)d_ws + (size_t)M_TOT * K_TOT;   // +16 MiB

    const int nx4 = M_TOT * K_TOT / 4;  // 8388608
    const int nw4 = N_TOT * K_TOT / 4;  // 4194304
    const int ncvt = nx4 + nw4;
    cvt_fused<<<(ncvt + 255) / 256, 256, 0, stream>>>(
        (const float4*)x, (const int4*)w, (unsigned*)Xq, (unsigned*)Wq, nx4, nw4);

    dim3 grid(M_TOT / BM, N_TOT / BN);  // 32 x 16
    gemm_i8<<<grid, 512, 0, stream>>>(Xq, Wq, scale, bias, out);
}

// Round 5
// 404.925 us; speedup vs baseline: 1.3957x; 1.3957x over previous
//
#include <hip/hip_runtime.h>
#include <stdint.h>

// ---------------------------------------------------------------------------
// QuantizedLinear via int8 MFMA: y[m,n] = s_x*s_w * (xq @ wq^T)[m,n] + bias[n]
// W int8 exact; x quantized at 6/127 (clamp +-6). int32 accum exact.
//
// R7: single-barrier read-ahead schedule (verified correct in R6) with
// spill-free register budget (R6 post-mortem: WRITE_SIZE 529 MB = scratch
// spills from acc=128 + frags 96 + addr ~ 254 regs at the 256/wave limit).
//   - BM=128, BN=256, BK=128; 8 waves (512 thr) of 64x64 -> acc[4][4]=64 regs.
//   - Phase = one k-step (64 i8): 16 MFMA/wave. 2 phases per K-tile.
//     Phase body: barrier; lgkm(0) [frags read last phase are done];
//     issue next phase's 8 ds_read_b128; (ks0 phases) stage tile T+2;
//     sched_barrier; setprio(1); 16 MFMA; setprio(0); ckpt.
//   - Frag sets S0/S1 ping-pong: 2 x (4 A + 4 B) x 4 regs = 64 regs.
//     Total ~150 regs -> no spill at 2 waves/SIMD.
//   - TRIPLE-buffered LDS (3 x 48 KB = 144 KB): tile T in buf[T%3]; all 6
//     stage loads (A:2 + B:4 per thread) for T+2 issued in ph(T,0) into
//     buf[(T+2)%3] (= buf of T-1, whose last frag-reads were drained by the
//     lgkm(0) in ph(T-1,1), confirmed for all waves by ph(T,0)'s barrier).
//   - One recurring guard: VMCNT(6) at end of every ks0-phase. At end of
//     ph(T,0) the 6 youngest loads are T+2's stages; waiting to <=6 forces
//     everything older (T+1's stages, issued ph(T-1,0), ~1400 cyc ago)
//     complete BEFORE the barrier opening ph(T,1), whose reads touch T+1.
//     Never vmcnt(0) in the main loop. Loop unrolled x3 tiles for static
//     buffer indices (NT=32 = 10x3 + 2-tile peel; peel guard VMCNT(0)).
//   - Chunk-XOR swizzle kept (bank-conflict counter measured 0 in R5/R6):
//     LDS(r,p) holds global chunk p^(r&7); conflict-free for ds_read_b128.
// ---------------------------------------------------------------------------

#define M_TOT 8192
#define N_TOT 4096
#define K_TOT 4096
#define BM 128
#define BN 256
#define BK 128              // i8 elements = 128 B per tile row = 8 x 16B chunks
#define NT (K_TOT / BK)     // 32 k-tiles

#define XCLAMP 6.0f

typedef int i32x4 __attribute__((ext_vector_type(4)));

__device__ __forceinline__ int q8(float v, float r) {
    float c = fminf(fmaxf(v * r, -127.0f), 127.0f);
    return (int)rintf(c);
}

__global__ __launch_bounds__(256) void cvt_fused(
    const float4* __restrict__ x, const int4* __restrict__ w,
    unsigned* __restrict__ xq, unsigned* __restrict__ wq, int nx4, int nw4) {
    int i = blockIdx.x * blockDim.x + threadIdx.x;
    if (i < nx4) {
        const float r = 127.0f / XCLAMP;
        float4 v = x[i];
        xq[i] = (unsigned)(q8(v.x, r) & 0xff)
              | ((unsigned)(q8(v.y, r) & 0xff) << 8)
              | ((unsigned)(q8(v.z, r) & 0xff) << 16)
              | ((unsigned)(q8(v.w, r) & 0xff) << 24);
    } else {
        int j = i - nx4;
        if (j >= nw4) return;
        int4 a = w[j];
        wq[j] = (unsigned)(a.x & 0xff)
              | ((unsigned)(a.y & 0xff) << 8)
              | ((unsigned)(a.z & 0xff) << 16)
              | ((unsigned)(a.w & 0xff) << 24);
    }
}

#define GLOAD_LDS16(gptr, lptr)                                                  \
    __builtin_amdgcn_global_load_lds(                                            \
        (const __attribute__((address_space(1))) void*)(gptr),                   \
        (__attribute__((address_space(3))) void*)(lptr), 16, 0, 0)

#define VMCNT(n) asm volatile("s_waitcnt vmcnt(" #n ")" ::: "memory")
#define NOSTG ((void)0)
#define NORD  ((void)0)
#define NOCKPT ((void)0)

// Stage one full K-tile (A: 128 rows, 2 loads/thread; B: 256 rows, 4/thread).
// Wave-load slot covers 8 linear LDS rows; global source pre-swizzled so
// LDS(r,p) holds global chunk p^(r&7)  (srow = lane>>3, r&7 == srow).
#define STAGE_TILE(GA, GB, LA, LB)                                               \
    { _Pragma("unroll")                                                          \
      for (int l = 0; l < 2; ++l) {                                              \
          const int r0_ = (((wave << 1) | l) << 3);                              \
          GLOAD_LDS16((GA) + (size_t)(r0_ + srow) * K_TOT + scol,                \
                      (LA) + r0_ * BK);                                          \
      }                                                                          \
      _Pragma("unroll")                                                          \
      for (int l = 0; l < 4; ++l) {                                              \
          const int r0_ = (((wave << 2) | l) << 3);                              \
          GLOAD_LDS16((GB) + (size_t)(r0_ + srow) * K_TOT + scol,                \
                      (LB) + r0_ * BK);                                          \
      } }

// Fragment reads for one k-step: 4 A + 4 B ds_read_b128 into a named set.
#define READS(DA, DB, LA, LB, POS)                                               \
    { _Pragma("unroll")                                                          \
      for (int i = 0; i < 4; ++i)                                                \
          DA[i] = *(const i32x4*)((LA) + (wm + i * 16 + frow) * BK + (POS));     \
      _Pragma("unroll")                                                          \
      for (int j = 0; j < 4; ++j)                                                \
          DB[j] = *(const i32x4*)((LB) + (wn + j * 16 + frow) * BK + (POS));     \
    }

// One phase: barrier; drain my frag reads (issued last phase, completed
// under last phase's MFMA); issue next phase's reads + (ks0) stages;
// 16 MFMA on set (SA,SB); counted-vmcnt checkpoint.
#define PHASE(RD, STG, SA, SB, CKPT)                                             \
    {                                                                            \
        __builtin_amdgcn_s_barrier();                                            \
        asm volatile("s_waitcnt lgkmcnt(0)" ::: "memory");                       \
        __builtin_amdgcn_sched_barrier(0);                                       \
        RD;                                                                      \
        STG;                                                                     \
        __builtin_amdgcn_sched_barrier(0);                                       \
        __builtin_amdgcn_s_setprio(1);                                           \
        _Pragma("unroll")                                                        \
        for (int i = 0; i < 4; ++i)                                              \
            _Pragma("unroll")                                                    \
            for (int j = 0; j < 4; ++j)                                          \
                acc[i][j] = __builtin_amdgcn_mfma_i32_16x16x64_i8(               \
                    SA[i], SB[j], acc[i][j], 0, 0, 0);                           \
        __builtin_amdgcn_s_setprio(0);                                           \
        CKPT;                                                                    \
    }

// C = A(MxK,i8) * B(NxK,i8)^T, epilogue: out = (s_x*s_w)*acc_i32 + bias[n]
__global__ __launch_bounds__(512, 2) void gemm_i8(
    const signed char* __restrict__ A, const signed char* __restrict__ B,
    const float* __restrict__ scale, const float* __restrict__ bias,
    float* __restrict__ out) {
    __shared__ alignas(16) signed char As[3][BM * BK];  // 3 x 16 KB
    __shared__ alignas(16) signed char Bs[3][BN * BK];  // 3 x 32 KB  (144 KB total)

    const int tid  = threadIdx.x;
    const int wave = tid >> 6;
    const int lane = tid & 63;
    const int bm = blockIdx.x;            // 0..63
    const int bn = blockIdx.y;            // 0..15
    const int wm = (wave >> 2) * 64;      // 2 M-waves
    const int wn = (wave & 3) * 64;       // 4 N-waves

    // fragment read coords: row R, k-chunk g = lane>>4 (+4 for k-step 1);
    // chunk g sits at LDS pos g ^ (R&7), R&7 == lane&7 for all frag rows.
    const int frow = lane & 15;
    const int pos0 = (((lane >> 4) + 0) ^ (lane & 7)) << 4;
    const int pos1 = (((lane >> 4) + 4) ^ (lane & 7)) << 4;
    // staging source coords (pre-swizzled global chunk)
    const int srow = lane >> 3;
    const int scol = ((lane & 7) ^ (lane >> 3)) << 4;

    const signed char* Ag = A + (size_t)bm * BM * K_TOT;
    const signed char* Bg = B + (size_t)bn * BN * K_TOT;

    i32x4 acc[4][4] = {};
    i32x4 a0[4], b0[4], a1[4], b1[4];     // frag sets S0/S1, ping-pong

    // ---- prologue: stage T0->buf0, T1->buf1; wait T0; read S0 <- T0 ks0 ----
    STAGE_TILE(Ag, Bg, As[0], Bs[0]);                       // 6 loads (T0)
    STAGE_TILE(Ag + BK, Bg + BK, As[1], Bs[1]);             // 6 loads (T1)
    VMCNT(6);                                               // T0 landed
    __builtin_amdgcn_s_barrier();
    READS(a0, b0, As[0], Bs[0], pos0);                      // T0 ks0 -> S0

    // ---- main loop: 10 iterations x 3 K-tiles x 2 phases ----
#pragma unroll 1
    for (int t = 0; t < NT - 2; t += 3) {
        const signed char* A2 = Ag + (size_t)(t + 2) * BK;
        const signed char* B2 = Bg + (size_t)(t + 2) * BK;
        const signed char* A3 = Ag + (size_t)(t + 3) * BK;
        const signed char* B3 = Bg + (size_t)(t + 3) * BK;
        const signed char* A4 = Ag + (size_t)(t + 4) * BK;
        const signed char* B4 = Bg + (size_t)(t + 4) * BK;

        // ph(t,0): MFMA S0 | read S1 <- (t,ks1,buf0) | stage t+2 -> buf2
        PHASE(READS(a1, b1, As[0], Bs[0], pos1),
              STAGE_TILE(A2, B2, As[2], Bs[2]), a0, b0, VMCNT(6))
        // ph(t,1): MFMA S1 | read S0 <- (t+1,ks0,buf1)
        PHASE(READS(a0, b0, As[1], Bs[1], pos0), NOSTG, a1, b1, NOCKPT)
        // ph(t+1,0): MFMA S0 | read S1 <- (t+1,ks1,buf1) | stage t+3 -> buf0
        PHASE(READS(a1, b1, As[1], Bs[1], pos1),
              STAGE_TILE(A3, B3, As[0], Bs[0]), a0, b0, VMCNT(6))
        // ph(t+1,1): MFMA S1 | read S0 <- (t+2,ks0,buf2)
        PHASE(READS(a0, b0, As[2], Bs[2], pos0), NOSTG, a1, b1, NOCKPT)
        // ph(t+2,0): MFMA S0 | read S1 <- (t+2,ks1,buf2) | stage t+4 -> buf1
        PHASE(READS(a1, b1, As[2], Bs[2], pos1),
              STAGE_TILE(A4, B4, As[1], Bs[1]), a0, b0, VMCNT(6))
        // ph(t+2,1): MFMA S1 | read S0 <- (t+3,ks0,buf0)
        PHASE(READS(a0, b0, As[0], Bs[0], pos0), NOSTG, a1, b1, NOCKPT)
    }

    // ---- peel tiles 30 (buf0) and 31 (buf1): no stages, drain once ----
    // t31 staged at ph(29,0); no younger loads -> VMCNT(0) (~2 phases old).
    PHASE(READS(a1, b1, As[0], Bs[0], pos1), NOSTG, a0, b0, VMCNT(0))  // ph(30,0)
    PHASE(READS(a0, b0, As[1], Bs[1], pos0), NOSTG, a1, b1, NOCKPT)    // ph(30,1)
    PHASE(READS(a1, b1, As[1], Bs[1], pos1), NOSTG, a0, b0, NOCKPT)    // ph(31,0)
    PHASE(NORD, NOSTG, a1, b1, NOCKPT)                                  // ph(31,1)

    // epilogue: C/D layout col=lane&15, row=(lane>>4)*4+reg (dtype-independent)
    const float s = scale[0] * (XCLAMP / 127.0f);
    const int colq = lane & 15;
    const int rowq = (lane >> 4) * 4;
#pragma unroll
    for (int i = 0; i < 4; ++i) {
        const int rbase = bm * BM + wm + i * 16 + rowq;
#pragma unroll
        for (int j = 0; j < 4; ++j) {
            const int c = bn * BN + wn + j * 16 + colq;
            const float bv = bias[c];
#pragma unroll
            for (int r = 0; r < 4; ++r)
                out[(size_t)(rbase + r) * N_TOT + c] = s * (float)acc[i][j][r] + bv;
        }
    }
}

extern "C" void kernel_launch(void* const* d_in, const int* in_sizes, int n_in,
                              void* d_out, int out_size, void* d_ws, size_t ws_size,
                              hipStream_t stream) {
    const float* x     = (const float*)d_in[0];   // [8192, 4096] fp32
    const int*   w     = (const int*)d_in[1];     // [4096, 4096] int32
    const float* scale = (const float*)d_in[2];   // [1]
    const float* bias  = (const float*)d_in[3];   // [4096]
    float* out = (float*)d_out;

    signed char* Xq = (signed char*)d_ws;                           // 32 MiB
    signed char* Wq = (signed char*)d_ws + (size_t)M_TOT * K_TOT;   // +16 MiB

    const int nx4 = M_TOT * K_TOT / 4;  // 8388608
    const int nw4 = N_TOT * K_TOT / 4;  // 4194304
    const int ncvt = nx4 + nw4;
    cvt_fused<<<(ncvt + 255) / 256, 256, 0, stream>>>(
        (const float4*)x, (const int4*)w, (unsigned*)Xq, (unsigned*)Wq, nx4, nw4);

    dim3 grid(M_TOT / BM, N_TOT / BN);  // 64 x 16
    gemm_i8<<<grid, 512, 0, stream>>>(Xq, Wq, scale, bias, out);
}